// Round 2
// baseline (1210.649 us; speedup 1.0000x reference)
//
#include <hip/hip_runtime.h>
#include <hip/hip_bf16.h>

// SharedMoE: T=8192 tokens, D=1024, F=4096, E=8 experts, top-2 + shared expert.
// R5: 256x256 tile, 8 waves, BK=32, 4-deep LDS ring (128KB), counted vmcnt(8)
//     (never drained in main loop), raw s_barrier (no compiler vmcnt(0) drain),
//     setprio around MFMA cluster. Phase-2 K-split=2 for launch balance.
//
// ws layout (BIG path, ~369.6 MB):
//   xb   0          : x bf16 [8192][1024]                16,777,216 B
//   w1t  16777216   : W1^T bf16 [9][4096][1024]          75,497,472 B (slot 8 = shared)
//   w2t  92274688   : W2^T bf16 [9][1024][4096]          75,497,472 B
//   h    167772160  : [24576][4096] bf16                201,326,592 B (routed rows at offs[e],
//                     shared rows at 16384; head 64KB doubles as router scratch)
//   tok_list/tok_w/counts/offs : ~0.5 MB
// Fallback (~235.5 MB): h is [8192][4096], per-expert serialized launches.

#define T_TOKENS 8192
#define DIM      1024
#define INTER    4096
#define NEXP     8

typedef short bf16x8 __attribute__((ext_vector_type(8)));
typedef float f32x4  __attribute__((ext_vector_type(4)));

#define ASM_VMCNT(n) asm volatile("s_waitcnt vmcnt(" #n ")" ::: "memory")
#define ASM_BAR()    asm volatile("s_barrier" ::: "memory")

__device__ __forceinline__ unsigned short f2b(float f) {
  union { float f; unsigned int u; } v; v.f = f;
  unsigned int u = v.u;
  return (unsigned short)((u + 0x7FFFu + ((u >> 16) & 1u)) >> 16);  // RNE
}

// async global->LDS DMA, 16B per lane; LDS dest = wave-uniform base + lane*16.
__device__ __forceinline__ void load_lds16(const unsigned short* g, unsigned short* l) {
  __builtin_amdgcn_global_load_lds(
      (const __attribute__((address_space(1))) void*)g,
      (__attribute__((address_space(3))) void*)l, 16, 0, 0);
}

__global__ void cast_x_kernel(const float* __restrict__ x, unsigned short* __restrict__ xb) {
  size_t i = ((size_t)blockIdx.x * 256 + threadIdx.x) * 4;
  float4 v = *(const float4*)(x + i);
  ushort4 o;
  o.x = f2b(v.x); o.y = f2b(v.y); o.z = f2b(v.z); o.w = f2b(v.w);
  *(ushort4*)(xb + i) = o;
}

// in: [K][N] fp32 (expert e<8 at routed + e*K*N, e==8 at shared). out: [N][K] bf16 per expert.
__global__ void transpose_cast_kernel(const float* __restrict__ routed,
                                      const float* __restrict__ shared_w,
                                      unsigned short* __restrict__ outb,
                                      int K, int N) {
  int e = blockIdx.z;
  const float* in = (e < NEXP) ? routed + (size_t)e * K * N : shared_w;
  unsigned short* out = outb + (size_t)e * K * N;
  __shared__ float tile[32][33];
  int n0 = blockIdx.x * 32, k0 = blockIdx.y * 32;
  int tid = threadIdx.x;
  int c = tid & 31, r0 = tid >> 5;
#pragma unroll
  for (int i = 0; i < 4; i++) {
    int r = r0 + i * 8;
    tile[r][c] = in[(size_t)(k0 + r) * N + n0 + c];
  }
  __syncthreads();
  int rr = tid >> 3;          // n-row within tile
  int c4 = (tid & 7) * 4;     // k group
  ushort4 o;
  o.x = f2b(tile[c4 + 0][rr]); o.y = f2b(tile[c4 + 1][rr]);
  o.z = f2b(tile[c4 + 2][rr]); o.w = f2b(tile[c4 + 3][rr]);
  *(ushort4*)(out + (size_t)(n0 + rr) * K + k0 + c4) = o;
}

// Router stage 1: fp32 logits, exact top-2 (lowest index on ties, like lax.top_k),
// softmax weight. No global atomics.
__global__ void router_topk_kernel(const float* __restrict__ x, const float* __restrict__ rw,
                                   int* __restrict__ top_idx, float* __restrict__ top_w) {
  int wv = threadIdx.x >> 6, lane = threadIdx.x & 63;
  int t = blockIdx.x * 4 + wv;
  const float* xr = x + (size_t)t * DIM;
  float a[8];
#pragma unroll
  for (int e = 0; e < 8; e++) a[e] = 0.f;
#pragma unroll
  for (int i = 0; i < 16; i++) {
    int d = i * 64 + lane;
    float xv = xr[d];
    float4 r0 = *(const float4*)(rw + d * 8);
    float4 r1 = *(const float4*)(rw + d * 8 + 4);
    a[0] += xv * r0.x; a[1] += xv * r0.y; a[2] += xv * r0.z; a[3] += xv * r0.w;
    a[4] += xv * r1.x; a[5] += xv * r1.y; a[6] += xv * r1.z; a[7] += xv * r1.w;
  }
#pragma unroll
  for (int s = 32; s; s >>= 1) {
#pragma unroll
    for (int e = 0; e < 8; e++) a[e] += __shfl_down(a[e], s);
  }
  if (lane == 0) {
    int be = 0; float bv = a[0];
#pragma unroll
    for (int e = 1; e < 8; e++) if (a[e] > bv) { bv = a[e]; be = e; }
    int be2 = -1; float bv2 = -3.4e38f;
#pragma unroll
    for (int e = 0; e < 8; e++) if (e != be && a[e] > bv2) { bv2 = a[e]; be2 = e; }
    float w0 = 1.f / (1.f + __expf(bv2 - bv));
    top_idx[t] = be | (be2 << 8);
    top_w[t] = w0;
  }
}

// Router stage 2: single-block bucket build (LDS atomics only) + prefix offsets.
__global__ void bucket_kernel(const int* __restrict__ top_idx, const float* __restrict__ top_w,
                              int* __restrict__ counts, int* __restrict__ offs,
                              int* __restrict__ tok_list, float* __restrict__ tok_w) {
  __shared__ int lcount[NEXP];
  int tid = threadIdx.x;
  if (tid < NEXP) lcount[tid] = 0;
  __syncthreads();
  for (int t = tid; t < T_TOKENS; t += 256) {
    int p = top_idx[t];
    float w0 = top_w[t];
    int e0 = p & 0xff, e1 = p >> 8;
    int s0 = atomicAdd(&lcount[e0], 1);
    tok_list[e0 * T_TOKENS + s0] = t; tok_w[e0 * T_TOKENS + s0] = w0;
    int s1 = atomicAdd(&lcount[e1], 1);
    tok_list[e1 * T_TOKENS + s1] = t; tok_w[e1 * T_TOKENS + s1] = 1.f - w0;
  }
  __syncthreads();
  if (tid == 0) {
    int run = 0;
    for (int e = 0; e < NEXP; e++) { counts[e] = lcount[e]; offs[e] = run; run += lcount[e]; }
    offs[NEXP] = run;  // == 2*T_TOKENS = 16384 always
  }
}

// PHASE 1: h[hbase+m] = relu(x_gathered[m] @ W1_e)      K=1024, nt=32
// PHASE 2: out[tok[m]] (+)= w[m] * (h[hbase+m] @ W2_e)  K=4096, batched: K-split 2, nt=64
// expert_arg >= 0: fixed expert, hbase=0, no K-split (serialized fallback).
// expert_arg <  0: batched; PHASE1 expert=z, PHASE2 expert=z%9, ksplit=z/9; accmode=1 -> atomicAdd.
//
// Tile 256x256, BK=32, 8 waves (2M x 4N), per-wave 128x64 = 8x4 16x16x32 MFMA frags.
// LDS: 4-deep ring of [256][32] bf16 for A and B (128 KB total), XOR chunk swizzle:
//   LDS slot (row, chunk c) holds global chunk c ^ (row&3); frag reads XOR the same.
//   DMA dest is linear (wave-uniform base + lane*16); source is pre-swizzled (rule #21).
// Pipeline: 3-tile lookahead, counted vmcnt (8 steady / 4 / 0 tail), raw s_barrier.
//   body(t): stage(t+3) -> compute(t) -> vmcnt(8) -> s_barrier.
//   Overwrite safety: stage(t+3) writes buf (t-1)&3, which all waves finished in
//   body(t-1) BEFORE its barrier. Read safety: body(t-1)'s vmcnt(8) retires the 4
//   oldest in-flight loads (= tile t), barrier publishes them to all waves.
template <int PHASE>
__global__ __launch_bounds__(512, 2) void gemm_kernel(
    const unsigned short* __restrict__ A, const unsigned short* __restrict__ Wt,
    unsigned short* __restrict__ H, float* __restrict__ Out,
    const int* __restrict__ counts, const int* __restrict__ offs,
    const int* __restrict__ tok_list, const float* __restrict__ tok_w,
    int expert_arg, int accmode) {
  const int Kd = (PHASE == 1) ? DIM : INTER;
  int zz = (int)blockIdx.z;
  int expert, ksp;
  if (expert_arg >= 0) { expert = expert_arg; ksp = 0; }
  else if (PHASE == 2) { expert = zz % 9; ksp = zz / 9; }
  else { expert = zz; ksp = 0; }

  int count = (expert < NEXP) ? counts[expert] : T_TOKENS;
  int m0 = blockIdx.y * 256;
  if (m0 >= count) return;
  int n0 = blockIdx.x * 256;
  int hbase = (expert_arg >= 0) ? 0 : ((expert < NEXP) ? offs[expert] : 2 * T_TOKENS);
  const unsigned short* Bt = Wt + (size_t)expert * (4096 * 1024);

  int nt, k0base;
  if (PHASE == 1) { nt = 32; k0base = 0; }
  else if (expert_arg >= 0) { nt = 128; k0base = 0; }
  else { nt = 64; k0base = ksp * 2048; }

  // 4-deep ring: per buffer 256 rows x 32 K-elems bf16 = 16 KB. A: 64KB, B: 64KB.
  __shared__ __align__(16) unsigned short As[4][256 * 32];
  __shared__ __align__(16) unsigned short Bs[4][256 * 32];

  int tid = threadIdx.x;
  int wv = tid >> 6, lane = tid & 63;
  int wv_m = wv >> 2, wv_n = wv & 3;         // 2 x 4 wave grid
  int m_woff = wv_m * 128, n_woff = wv_n * 64;

  // ---- staging setup: per tile, per thread: 2 A-issues + 2 B-issues (4 loads) ----
  // Issue (wv,j) covers tile rows [ (wv*2+j)*16, +16 ). Lane l -> local row +(l>>2),
  // LDS chunk slot (l&3); source reads global chunk (l&3)^(row&3)  [row&3 == (l>>2)&3].
  int gc = (((lane & 3) ^ ((lane >> 2) & 3)) * 8);   // swizzled global elem offset in 32-K window
  const unsigned short* aG[2];
  const unsigned short* bG[2];
  int regBase[2];
#pragma unroll
  for (int j = 0; j < 2; j++) {
    int reg = wv * 2 + j;                    // 0..15
    int lr = reg * 16 + (lane >> 2);         // tile row 0..255
    int src;
    if (PHASE == 1) {
      int m = m0 + lr;
      src = (expert < NEXP) ? ((m < count) ? tok_list[expert * T_TOKENS + m] : 0) : m;
    } else {
      src = hbase + m0 + lr;                 // h rows bucket-ordered (garbage rows masked at store)
    }
    aG[j] = A + (size_t)src * Kd + k0base + gc;
    bG[j] = Bt + (size_t)(n0 + lr) * Kd + k0base + gc;
    regBase[j] = reg * 512;                  // elems into buffer (16 rows * 32)
  }

  f32x4 acc[8][4];
#pragma unroll
  for (int mf = 0; mf < 8; mf++)
#pragma unroll
    for (int nf = 0; nf < 4; nf++) acc[mf][nf] = (f32x4)0.f;

  int l15 = lane & 15, q = lane >> 4;
  int cofs = ((q ^ (l15 & 3)) * 8);          // frag-read swizzled chunk -> elem offset
  int aBase = (m_woff + l15) * 32 + cofs;
  int bBase = (n_woff + l15) * 32 + cofs;

  auto stage = [&](int buf) {
#pragma unroll
    for (int j = 0; j < 2; j++) {
      load_lds16(aG[j], &As[buf][regBase[j]]);
      load_lds16(bG[j], &Bs[buf][regBase[j]]);
      aG[j] += 32; bG[j] += 32;
    }
  };

  auto compute_tile = [&](int buf) {
    const unsigned short* Ab = &As[buf][0];
    const unsigned short* Bb = &Bs[buf][0];
    bf16x8 af[8], bfr[4];
#pragma unroll
    for (int mf = 0; mf < 8; mf++) af[mf] = *(const bf16x8*)&Ab[aBase + mf * 512];
#pragma unroll
    for (int nf = 0; nf < 4; nf++) bfr[nf] = *(const bf16x8*)&Bb[bBase + nf * 512];
    __builtin_amdgcn_s_setprio(1);
#pragma unroll
    for (int mf = 0; mf < 8; mf++)
#pragma unroll
      for (int nf = 0; nf < 4; nf++)
        acc[mf][nf] = __builtin_amdgcn_mfma_f32_16x16x32_bf16(af[mf], bfr[nf], acc[mf][nf], 0, 0, 0);
    __builtin_amdgcn_s_setprio(0);
  };

  // ---- pipelined K loop (nt >= 4 always: 32/64/128) ----
  stage(0); stage(1); stage(2);
  ASM_VMCNT(8); ASM_BAR();                   // 12 in flight -> tile 0 landed, published
  int t = 0;
  for (; t + 3 < nt; ++t) {
    stage((t + 3) & 3);                      // overwrites buf (t-1)&3 (freed by prev barrier)
    compute_tile(t & 3);
    ASM_VMCNT(8); ASM_BAR();                 // tile t+1 landed, published; 8 loads stay in flight
  }
  compute_tile(t & 3); ASM_VMCNT(4); ASM_BAR(); ++t;
  compute_tile(t & 3); ASM_VMCNT(0); ASM_BAR(); ++t;
  compute_tile(t & 3);

  // C/D layout (m89-verified): col = lane&15, row = (lane>>4)*4 + i
  if (PHASE == 1) {
#pragma unroll
    for (int mf = 0; mf < 8; mf++)
#pragma unroll
      for (int i = 0; i < 4; i++) {
        int m = m0 + m_woff + mf * 16 + q * 4 + i;
        if (m < count) {
#pragma unroll
          for (int nf = 0; nf < 4; nf++) {
            int f = n0 + n_woff + nf * 16 + l15;
            float v = acc[mf][nf][i];
            H[(size_t)(hbase + m) * INTER + f] = f2b(v > 0.f ? v : 0.f);
          }
        }
      }
  } else {
#pragma unroll
    for (int mf = 0; mf < 8; mf++)
#pragma unroll
      for (int i = 0; i < 4; i++) {
        int m = m0 + m_woff + mf * 16 + q * 4 + i;
        if (m < count) {
          int tokn; float swt;
          if (expert < NEXP) { tokn = tok_list[expert * T_TOKENS + m]; swt = tok_w[expert * T_TOKENS + m]; }
          else { tokn = m; swt = 1.f; }
          float* orow = Out + (size_t)tokn * DIM;
#pragma unroll
          for (int nf = 0; nf < 4; nf++) {
            int d = n0 + n_woff + nf * 16 + l15;
            float v = swt * acc[mf][nf][i];
            if (accmode) atomicAdd(orow + d, v);          // batched: out pre-zeroed, K-split safe
            else if (expert < NEXP) orow[d] += v;          // serialized routed
            else orow[d] = v;                              // serialized shared (init)
          }
        }
      }
  }
}

extern "C" void kernel_launch(void* const* d_in, const int* in_sizes, int n_in,
                              void* d_out, int out_size, void* d_ws, size_t ws_size,
                              hipStream_t stream) {
  const float* x   = (const float*)d_in[0];
  const float* sw1 = (const float*)d_in[1];
  const float* sw2 = (const float*)d_in[2];
  const float* rw1 = (const float*)d_in[3];
  const float* rw2 = (const float*)d_in[4];
  const float* rtw = (const float*)d_in[5];
  float* out = (float*)d_out;

  char* ws = (char*)d_ws;
  unsigned short* xb  = (unsigned short*)(ws);
  unsigned short* w1t = (unsigned short*)(ws + 16777216);
  unsigned short* w2t = (unsigned short*)(ws + 92274688);
  unsigned short* h   = (unsigned short*)(ws + 167772160);
  // router scratch overlaid on head of h (consumed by bucket_kernel before h is written)
  int*   top_idx      = (int*)(ws + 167772160);
  float* top_w        = (float*)(ws + 167772160 + 32768);

  const size_t H_BIG  = (size_t)24576 * 4096 * 2;        // 201,326,592
  const size_t H_SMALL= (size_t)8192  * 4096 * 2;        //  67,108,864
  const size_t NEED_BIG = 167772160 + H_BIG + 262144 * 2 + 256;
  bool big = ws_size >= NEED_BIG;
  size_t tail = 167772160 + (big ? H_BIG : H_SMALL);
  int*   tok_list = (int*)(ws + tail);
  float* tok_w    = (float*)(ws + tail + 262144);
  int*   counts   = (int*)(ws + tail + 524288);
  int*   offs     = (int*)(ws + tail + 524288 + 64);

  cast_x_kernel<<<(T_TOKENS * DIM) / (256 * 4), 256, 0, stream>>>(x, xb);
  transpose_cast_kernel<<<dim3(128, 32, 9), 256, 0, stream>>>(rw1, sw1, w1t, 1024, 4096);
  transpose_cast_kernel<<<dim3(32, 128, 9), 256, 0, stream>>>(rw2, sw2, w2t, 4096, 1024);
  router_topk_kernel<<<T_TOKENS / 4, 256, 0, stream>>>(x, rtw, top_idx, top_w);
  bucket_kernel<<<1, 256, 0, stream>>>(top_idx, top_w, counts, offs, tok_list, tok_w);

  if (big) {
    hipMemsetAsync(out, 0, (size_t)T_TOKENS * DIM * sizeof(float), stream);
    // all 9 experts (z=8 is shared), one launch per phase; p2 K-split=2 (z=18), atomic acc.
    gemm_kernel<1><<<dim3(16, 32, 9), 512, 0, stream>>>(xb, w1t, h, nullptr,
                                                        counts, offs, tok_list, tok_w, -1, 1);
    gemm_kernel<2><<<dim3(4, 32, 18), 512, 0, stream>>>(h, w2t, nullptr, out,
                                                        counts, offs, tok_list, tok_w, -1, 1);
  } else {
    // serialized fallback: shared first (plain-store init), routed accumulate
    gemm_kernel<1><<<dim3(16, 32), 512, 0, stream>>>(xb, w1t, h, nullptr,
                                                     counts, offs, tok_list, tok_w, 8, 0);
    gemm_kernel<2><<<dim3(4, 32), 512, 0, stream>>>(h, w2t, nullptr, out,
                                                    counts, offs, tok_list, tok_w, 8, 0);
    for (int e = 0; e < 8; e++) {
      gemm_kernel<1><<<dim3(16, 32), 512, 0, stream>>>(xb, w1t, h, nullptr,
                                                       counts, offs, tok_list, tok_w, e, 0);
      gemm_kernel<2><<<dim3(4, 32), 512, 0, stream>>>(h, w2t, nullptr, out,
                                                      counts, offs, tok_list, tok_w, e, 0);
    }
  }
}

// Round 3
// 1171.700 us; speedup vs baseline: 1.0332x; 1.0332x over previous
//
#include <hip/hip_runtime.h>
#include <hip/hip_bf16.h>

// SharedMoE: T=8192 tokens, D=1024, F=4096, E=8 experts, top-2 + shared expert.
// R6: R5's ring-4 counted-vmcnt pipeline (verified race-free) + conflict-free LDS
//     layout: tile A/B (256 rows x 32 K) stored as 128 paired rows of 128 B
//     (LDS row r = tile rows 2r,2r+1 as 8 chunks, XOR(r&7) swizzle) — exactly the
//     R3 geometry that measured 0 bank conflicts. DMA dest linear, source swizzled.
//
// ws layout (BIG path, ~369.6 MB):
//   xb   0          : x bf16 [8192][1024]                16,777,216 B
//   w1t  16777216   : W1^T bf16 [9][4096][1024]          75,497,472 B (slot 8 = shared)
//   w2t  92274688   : W2^T bf16 [9][1024][4096]          75,497,472 B
//   h    167772160  : [24576][4096] bf16                201,326,592 B (routed rows at offs[e],
//                     shared rows at 16384; head 64KB doubles as router scratch)
//   tok_list/tok_w/counts/offs : ~0.5 MB
// Fallback (~235.5 MB): h is [8192][4096], per-expert serialized launches.

#define T_TOKENS 8192
#define DIM      1024
#define INTER    4096
#define NEXP     8

typedef short bf16x8 __attribute__((ext_vector_type(8)));
typedef float f32x4  __attribute__((ext_vector_type(4)));

#define ASM_VMCNT(n) asm volatile("s_waitcnt vmcnt(" #n ")" ::: "memory")
#define ASM_BAR()    asm volatile("s_barrier" ::: "memory")

__device__ __forceinline__ unsigned short f2b(float f) {
  union { float f; unsigned int u; } v; v.f = f;
  unsigned int u = v.u;
  return (unsigned short)((u + 0x7FFFu + ((u >> 16) & 1u)) >> 16);  // RNE
}

// async global->LDS DMA, 16B per lane; LDS dest = wave-uniform base + lane*16.
__device__ __forceinline__ void load_lds16(const unsigned short* g, unsigned short* l) {
  __builtin_amdgcn_global_load_lds(
      (const __attribute__((address_space(1))) void*)g,
      (__attribute__((address_space(3))) void*)l, 16, 0, 0);
}

__global__ void cast_x_kernel(const float* __restrict__ x, unsigned short* __restrict__ xb) {
  size_t i = ((size_t)blockIdx.x * 256 + threadIdx.x) * 4;
  float4 v = *(const float4*)(x + i);
  ushort4 o;
  o.x = f2b(v.x); o.y = f2b(v.y); o.z = f2b(v.z); o.w = f2b(v.w);
  *(ushort4*)(xb + i) = o;
}

// in: [K][N] fp32 (expert e<8 at routed + e*K*N, e==8 at shared). out: [N][K] bf16 per expert.
__global__ void transpose_cast_kernel(const float* __restrict__ routed,
                                      const float* __restrict__ shared_w,
                                      unsigned short* __restrict__ outb,
                                      int K, int N) {
  int e = blockIdx.z;
  const float* in = (e < NEXP) ? routed + (size_t)e * K * N : shared_w;
  unsigned short* out = outb + (size_t)e * K * N;
  __shared__ float tile[32][33];
  int n0 = blockIdx.x * 32, k0 = blockIdx.y * 32;
  int tid = threadIdx.x;
  int c = tid & 31, r0 = tid >> 5;
#pragma unroll
  for (int i = 0; i < 4; i++) {
    int r = r0 + i * 8;
    tile[r][c] = in[(size_t)(k0 + r) * N + n0 + c];
  }
  __syncthreads();
  int rr = tid >> 3;          // n-row within tile
  int c4 = (tid & 7) * 4;     // k group
  ushort4 o;
  o.x = f2b(tile[c4 + 0][rr]); o.y = f2b(tile[c4 + 1][rr]);
  o.z = f2b(tile[c4 + 2][rr]); o.w = f2b(tile[c4 + 3][rr]);
  *(ushort4*)(out + (size_t)(n0 + rr) * K + k0 + c4) = o;
}

// Router stage 1: fp32 logits, exact top-2 (lowest index on ties, like lax.top_k),
// softmax weight. No global atomics.
__global__ void router_topk_kernel(const float* __restrict__ x, const float* __restrict__ rw,
                                   int* __restrict__ top_idx, float* __restrict__ top_w) {
  int wv = threadIdx.x >> 6, lane = threadIdx.x & 63;
  int t = blockIdx.x * 4 + wv;
  const float* xr = x + (size_t)t * DIM;
  float a[8];
#pragma unroll
  for (int e = 0; e < 8; e++) a[e] = 0.f;
#pragma unroll
  for (int i = 0; i < 16; i++) {
    int d = i * 64 + lane;
    float xv = xr[d];
    float4 r0 = *(const float4*)(rw + d * 8);
    float4 r1 = *(const float4*)(rw + d * 8 + 4);
    a[0] += xv * r0.x; a[1] += xv * r0.y; a[2] += xv * r0.z; a[3] += xv * r0.w;
    a[4] += xv * r1.x; a[5] += xv * r1.y; a[6] += xv * r1.z; a[7] += xv * r1.w;
  }
#pragma unroll
  for (int s = 32; s; s >>= 1) {
#pragma unroll
    for (int e = 0; e < 8; e++) a[e] += __shfl_down(a[e], s);
  }
  if (lane == 0) {
    int be = 0; float bv = a[0];
#pragma unroll
    for (int e = 1; e < 8; e++) if (a[e] > bv) { bv = a[e]; be = e; }
    int be2 = -1; float bv2 = -3.4e38f;
#pragma unroll
    for (int e = 0; e < 8; e++) if (e != be && a[e] > bv2) { bv2 = a[e]; be2 = e; }
    float w0 = 1.f / (1.f + __expf(bv2 - bv));
    top_idx[t] = be | (be2 << 8);
    top_w[t] = w0;
  }
}

// Router stage 2: single-block bucket build (LDS atomics only) + prefix offsets.
__global__ void bucket_kernel(const int* __restrict__ top_idx, const float* __restrict__ top_w,
                              int* __restrict__ counts, int* __restrict__ offs,
                              int* __restrict__ tok_list, float* __restrict__ tok_w) {
  __shared__ int lcount[NEXP];
  int tid = threadIdx.x;
  if (tid < NEXP) lcount[tid] = 0;
  __syncthreads();
  for (int t = tid; t < T_TOKENS; t += 256) {
    int p = top_idx[t];
    float w0 = top_w[t];
    int e0 = p & 0xff, e1 = p >> 8;
    int s0 = atomicAdd(&lcount[e0], 1);
    tok_list[e0 * T_TOKENS + s0] = t; tok_w[e0 * T_TOKENS + s0] = w0;
    int s1 = atomicAdd(&lcount[e1], 1);
    tok_list[e1 * T_TOKENS + s1] = t; tok_w[e1 * T_TOKENS + s1] = 1.f - w0;
  }
  __syncthreads();
  if (tid == 0) {
    int run = 0;
    for (int e = 0; e < NEXP; e++) { counts[e] = lcount[e]; offs[e] = run; run += lcount[e]; }
    offs[NEXP] = run;  // == 2*T_TOKENS = 16384 always
  }
}

// PHASE 1: h[hbase+m] = relu(x_gathered[m] @ W1_e)      K=1024, nt=32
// PHASE 2: out[tok[m]] (+)= w[m] * (h[hbase+m] @ W2_e)  K=4096, batched: K-split 2, nt=64
// expert_arg >= 0: fixed expert, hbase=0, no K-split (serialized fallback).
// expert_arg <  0: batched; PHASE1 expert=z, PHASE2 expert=z%9, ksplit=z/9; accmode=1 -> atomicAdd.
//
// Tile 256x256, BK=32, 8 waves (2M x 4N), per-wave 128x64 = 8x4 16x16x32 MFMA frags.
// LDS: 4-deep ring of 16KB buffers for A and B (128 KB total). Within a buffer,
//   tile (256 rows x 32 K bf16) is stored as 128 paired rows of 128 B:
//     LDS row r (0..127), chunk slot s (0..7, 16 B each) holds global chunk
//     g = s ^ (r&7), where g>>2 = row parity (tile row = 2r + (g>>2)) and
//     g&3 = k-chunk (k elems (g&3)*8 .. +8).
//   This is R3's zero-conflict [128][64]+XOR(row&7) geometry. DMA dest is linear
//   (wave-uniform base + lane*16); the SOURCE address absorbs the swizzle (rule #21).
// Pipeline: 3-tile lookahead, counted vmcnt (8 steady / 4 / 0 tail), raw s_barrier.
//   body(t): stage(t+3) -> compute(t) -> vmcnt(8) -> s_barrier.
//   Overwrite safety: stage(t+3) writes buf (t-1)&3, finished by all waves in
//   body(t-1) before its barrier. Read safety: body(t-1)'s vmcnt(8) retires the 4
//   oldest in-flight loads (= tile t), barrier publishes them to all waves.
template <int PHASE>
__global__ __launch_bounds__(512, 2) void gemm_kernel(
    const unsigned short* __restrict__ A, const unsigned short* __restrict__ Wt,
    unsigned short* __restrict__ H, float* __restrict__ Out,
    const int* __restrict__ counts, const int* __restrict__ offs,
    const int* __restrict__ tok_list, const float* __restrict__ tok_w,
    int expert_arg, int accmode) {
  const int Kd = (PHASE == 1) ? DIM : INTER;
  int zz = (int)blockIdx.z;
  int expert, ksp;
  if (expert_arg >= 0) { expert = expert_arg; ksp = 0; }
  else if (PHASE == 2) { expert = zz % 9; ksp = zz / 9; }
  else { expert = zz; ksp = 0; }

  int count = (expert < NEXP) ? counts[expert] : T_TOKENS;
  int m0 = blockIdx.y * 256;
  if (m0 >= count) return;
  int n0 = blockIdx.x * 256;
  int hbase = (expert_arg >= 0) ? 0 : ((expert < NEXP) ? offs[expert] : 2 * T_TOKENS);
  const unsigned short* Bt = Wt + (size_t)expert * (4096 * 1024);

  int nt, k0base;
  if (PHASE == 1) { nt = 32; k0base = 0; }
  else if (expert_arg >= 0) { nt = 128; k0base = 0; }
  else { nt = 64; k0base = ksp * 2048; }

  // 4-deep ring: per buffer 256 rows x 32 K-elems bf16 = 16 KB. A: 64KB, B: 64KB.
  __shared__ __align__(16) unsigned short As[4][256 * 32];
  __shared__ __align__(16) unsigned short Bs[4][256 * 32];

  int tid = threadIdx.x;
  int wv = tid >> 6, lane = tid & 63;
  int wv_m = wv >> 2, wv_n = wv & 3;         // 2 x 4 wave grid
  int m_woff = wv_m * 128, n_woff = wv_n * 64;

  // ---- staging setup: per tile per thread: 2 A-issues + 2 B-issues (4 loads) ----
  // Issue j covers LDS bytes [j*8192 + wv*1024, +1024) of the buffer; lane writes
  // 16 B at LDS row r = j*64 + wv*8 + (lane>>3), slot = lane&7. That slot holds
  // global chunk g = (lane&7) ^ (lane>>3)  [since (j*64+wv*8)&7 == 0]:
  //   tile row = j*128 + wv*16 + 2*(lane>>3) + (g>>2), k offset = (g&3)*8.
  int g = (lane & 7) ^ (lane >> 3);
  int kc = (g & 3) * 8;
  const unsigned short* aG[2];
  const unsigned short* bG[2];
  int ldsOff[2];
#pragma unroll
  for (int j = 0; j < 2; j++) {
    int tr = j * 128 + wv * 16 + 2 * (lane >> 3) + (g >> 2);   // tile row 0..255
    int srcA;
    if (PHASE == 1) {
      int m = m0 + tr;
      srcA = (expert < NEXP) ? ((m < count) ? tok_list[expert * T_TOKENS + m] : 0) : m;
    } else {
      srcA = hbase + m0 + tr;                // h rows bucket-ordered (garbage rows masked at store)
    }
    aG[j] = A + (size_t)srcA * Kd + k0base + kc;
    bG[j] = Bt + (size_t)(n0 + tr) * Kd + k0base + kc;
    ldsOff[j] = j * 4096 + wv * 512;         // elem offset of wave-uniform LDS base
  }

  f32x4 acc[8][4];
#pragma unroll
  for (int mf = 0; mf < 8; mf++)
#pragma unroll
    for (int nf = 0; nf < 4; nf++) acc[mf][nf] = (f32x4)0.f;

  // ---- frag-read addressing ----
  // Lane (l15, q) wants tile row = base + l15, k = q*8..q*8+7:
  //   r = (base>>1) + (l15>>1)   [base>>1 ≡ 0 mod 8 for all bases used]
  //   g = ((l15&1)<<2) | q ; slot = g ^ (r&7) = g ^ (l15>>1)
  // Per slot: 8 lanes, 8 distinct rows -> R3's measured-zero-conflict pattern.
  int l15 = lane & 15, q = lane >> 4;
  int slot = (((l15 & 1) << 2) | q) ^ (l15 >> 1);
  int aBase = (wv_m * 64 + (l15 >> 1)) * 64 + slot * 8;   // elems; mf stride = 8 rows = 512
  int bBase = (wv_n * 32 + (l15 >> 1)) * 64 + slot * 8;   // elems; nf stride = 8 rows = 512

  auto stage = [&](int buf) {
#pragma unroll
    for (int j = 0; j < 2; j++) {
      load_lds16(aG[j], &As[buf][ldsOff[j]]);
      load_lds16(bG[j], &Bs[buf][ldsOff[j]]);
      aG[j] += 32; bG[j] += 32;
    }
  };

  auto compute_tile = [&](int buf) {
    const unsigned short* Ab = &As[buf][0];
    const unsigned short* Bb = &Bs[buf][0];
    bf16x8 af[8], bfr[4];
#pragma unroll
    for (int mf = 0; mf < 8; mf++) af[mf] = *(const bf16x8*)&Ab[aBase + mf * 512];
#pragma unroll
    for (int nf = 0; nf < 4; nf++) bfr[nf] = *(const bf16x8*)&Bb[bBase + nf * 512];
    __builtin_amdgcn_s_setprio(1);
#pragma unroll
    for (int mf = 0; mf < 8; mf++)
#pragma unroll
      for (int nf = 0; nf < 4; nf++)
        acc[mf][nf] = __builtin_amdgcn_mfma_f32_16x16x32_bf16(af[mf], bfr[nf], acc[mf][nf], 0, 0, 0);
    __builtin_amdgcn_s_setprio(0);
  };

  // ---- pipelined K loop (nt >= 4 always: 32/64/128) ----
  stage(0); stage(1); stage(2);
  ASM_VMCNT(8); ASM_BAR();                   // 12 in flight -> tile 0 landed, published
  int t = 0;
  for (; t + 3 < nt; ++t) {
    stage((t + 3) & 3);                      // overwrites buf (t-1)&3 (freed by prev barrier)
    compute_tile(t & 3);
    ASM_VMCNT(8); ASM_BAR();                 // tile t+1 landed, published; 8 loads stay in flight
  }
  compute_tile(t & 3); ASM_VMCNT(4); ASM_BAR(); ++t;
  compute_tile(t & 3); ASM_VMCNT(0); ASM_BAR(); ++t;
  compute_tile(t & 3);

  // C/D layout (m89-verified): col = lane&15, row = (lane>>4)*4 + i
  if (PHASE == 1) {
#pragma unroll
    for (int mf = 0; mf < 8; mf++)
#pragma unroll
      for (int i = 0; i < 4; i++) {
        int m = m0 + m_woff + mf * 16 + q * 4 + i;
        if (m < count) {
#pragma unroll
          for (int nf = 0; nf < 4; nf++) {
            int f = n0 + n_woff + nf * 16 + l15;
            float v = acc[mf][nf][i];
            H[(size_t)(hbase + m) * INTER + f] = f2b(v > 0.f ? v : 0.f);
          }
        }
      }
  } else {
#pragma unroll
    for (int mf = 0; mf < 8; mf++)
#pragma unroll
      for (int i = 0; i < 4; i++) {
        int m = m0 + m_woff + mf * 16 + q * 4 + i;
        if (m < count) {
          int tokn; float swt;
          if (expert < NEXP) { tokn = tok_list[expert * T_TOKENS + m]; swt = tok_w[expert * T_TOKENS + m]; }
          else { tokn = m; swt = 1.f; }
          float* orow = Out + (size_t)tokn * DIM;
#pragma unroll
          for (int nf = 0; nf < 4; nf++) {
            int d = n0 + n_woff + nf * 16 + l15;
            float v = swt * acc[mf][nf][i];
            if (accmode) atomicAdd(orow + d, v);          // batched: out pre-zeroed, K-split safe
            else if (expert < NEXP) orow[d] += v;          // serialized routed
            else orow[d] = v;                              // serialized shared (init)
          }
        }
      }
  }
}

extern "C" void kernel_launch(void* const* d_in, const int* in_sizes, int n_in,
                              void* d_out, int out_size, void* d_ws, size_t ws_size,
                              hipStream_t stream) {
  const float* x   = (const float*)d_in[0];
  const float* sw1 = (const float*)d_in[1];
  const float* sw2 = (const float*)d_in[2];
  const float* rw1 = (const float*)d_in[3];
  const float* rw2 = (const float*)d_in[4];
  const float* rtw = (const float*)d_in[5];
  float* out = (float*)d_out;

  char* ws = (char*)d_ws;
  unsigned short* xb  = (unsigned short*)(ws);
  unsigned short* w1t = (unsigned short*)(ws + 16777216);
  unsigned short* w2t = (unsigned short*)(ws + 92274688);
  unsigned short* h   = (unsigned short*)(ws + 167772160);
  // router scratch overlaid on head of h (consumed by bucket_kernel before h is written)
  int*   top_idx      = (int*)(ws + 167772160);
  float* top_w        = (float*)(ws + 167772160 + 32768);

  const size_t H_BIG  = (size_t)24576 * 4096 * 2;        // 201,326,592
  const size_t H_SMALL= (size_t)8192  * 4096 * 2;        //  67,108,864
  const size_t NEED_BIG = 167772160 + H_BIG + 262144 * 2 + 256;
  bool big = ws_size >= NEED_BIG;
  size_t tail = 167772160 + (big ? H_BIG : H_SMALL);
  int*   tok_list = (int*)(ws + tail);
  float* tok_w    = (float*)(ws + tail + 262144);
  int*   counts   = (int*)(ws + tail + 524288);
  int*   offs     = (int*)(ws + tail + 524288 + 64);

  cast_x_kernel<<<(T_TOKENS * DIM) / (256 * 4), 256, 0, stream>>>(x, xb);
  transpose_cast_kernel<<<dim3(128, 32, 9), 256, 0, stream>>>(rw1, sw1, w1t, 1024, 4096);
  transpose_cast_kernel<<<dim3(32, 128, 9), 256, 0, stream>>>(rw2, sw2, w2t, 4096, 1024);
  router_topk_kernel<<<T_TOKENS / 4, 256, 0, stream>>>(x, rtw, top_idx, top_w);
  bucket_kernel<<<1, 256, 0, stream>>>(top_idx, top_w, counts, offs, tok_list, tok_w);

  if (big) {
    hipMemsetAsync(out, 0, (size_t)T_TOKENS * DIM * sizeof(float), stream);
    // all 9 experts (z=8 is shared), one launch per phase; p2 K-split=2 (z=18), atomic acc.
    gemm_kernel<1><<<dim3(16, 32, 9), 512, 0, stream>>>(xb, w1t, h, nullptr,
                                                        counts, offs, tok_list, tok_w, -1, 1);
    gemm_kernel<2><<<dim3(4, 32, 18), 512, 0, stream>>>(h, w2t, nullptr, out,
                                                        counts, offs, tok_list, tok_w, -1, 1);
  } else {
    // serialized fallback: shared first (plain-store init), routed accumulate
    gemm_kernel<1><<<dim3(16, 32), 512, 0, stream>>>(xb, w1t, h, nullptr,
                                                     counts, offs, tok_list, tok_w, 8, 0);
    gemm_kernel<2><<<dim3(4, 32), 512, 0, stream>>>(h, w2t, nullptr, out,
                                                    counts, offs, tok_list, tok_w, 8, 0);
    for (int e = 0; e < 8; e++) {
      gemm_kernel<1><<<dim3(16, 32), 512, 0, stream>>>(xb, w1t, h, nullptr,
                                                       counts, offs, tok_list, tok_w, e, 0);
      gemm_kernel<2><<<dim3(4, 32), 512, 0, stream>>>(h, w2t, nullptr, out,
                                                      counts, offs, tok_list, tok_w, e, 0);
    }
  }
}

// Round 4
// 1068.632 us; speedup vs baseline: 1.1329x; 1.0964x over previous
//
#include <hip/hip_runtime.h>
#include <hip/hip_bf16.h>

// SharedMoE: T=8192 tokens, D=1024, F=4096, E=8 experts, top-2 + shared expert.
// R7: R6's ring-4 counted-vmcnt pipeline + zero-conflict LDS layout (verified),
//     with the K-loop body re-ordered into the m201-style 2-phase-per-BK32 template:
//       phase A: 8 ds_reads (af_lo,bfr) + half stage -> bar -> lgkm(0) -> schedbar
//                -> setprio(1) 16 MFMA setprio(0) -> bar
//       phase B: 4 ds_reads (af_hi) + half stage + vmcnt(8) -> bar -> lgkm(0)
//                -> schedbar -> setprio(1) 16 MFMA setprio(0) -> bar
//     Same barrier/phase density as the m201 8-phase-per-K64 schedule; creates
//     wave role diversity so barrier waits overlap other waves' MFMA clusters.
//
// ws layout (BIG path, ~369.6 MB):
//   xb   0          : x bf16 [8192][1024]                16,777,216 B
//   w1t  16777216   : W1^T bf16 [9][4096][1024]          75,497,472 B (slot 8 = shared)
//   w2t  92274688   : W2^T bf16 [9][1024][4096]          75,497,472 B
//   h    167772160  : [24576][4096] bf16                201,326,592 B (routed rows at offs[e],
//                     shared rows at 16384; head 64KB doubles as router scratch)
//   tok_list/tok_w/counts/offs : ~0.5 MB
// Fallback (~235.5 MB): h is [8192][4096], per-expert serialized launches.

#define T_TOKENS 8192
#define DIM      1024
#define INTER    4096
#define NEXP     8

typedef short bf16x8 __attribute__((ext_vector_type(8)));
typedef float f32x4  __attribute__((ext_vector_type(4)));

#define ASM_VMCNT(n) asm volatile("s_waitcnt vmcnt(" #n ")" ::: "memory")
#define ASM_LGKM0()  asm volatile("s_waitcnt lgkmcnt(0)" ::: "memory")
#define ASM_BAR()    asm volatile("s_barrier" ::: "memory")

__device__ __forceinline__ unsigned short f2b(float f) {
  union { float f; unsigned int u; } v; v.f = f;
  unsigned int u = v.u;
  return (unsigned short)((u + 0x7FFFu + ((u >> 16) & 1u)) >> 16);  // RNE
}

// async global->LDS DMA, 16B per lane; LDS dest = wave-uniform base + lane*16.
__device__ __forceinline__ void load_lds16(const unsigned short* g, unsigned short* l) {
  __builtin_amdgcn_global_load_lds(
      (const __attribute__((address_space(1))) void*)g,
      (__attribute__((address_space(3))) void*)l, 16, 0, 0);
}

__global__ void cast_x_kernel(const float* __restrict__ x, unsigned short* __restrict__ xb) {
  size_t i = ((size_t)blockIdx.x * 256 + threadIdx.x) * 4;
  float4 v = *(const float4*)(x + i);
  ushort4 o;
  o.x = f2b(v.x); o.y = f2b(v.y); o.z = f2b(v.z); o.w = f2b(v.w);
  *(ushort4*)(xb + i) = o;
}

// in: [K][N] fp32 (expert e<8 at routed + e*K*N, e==8 at shared). out: [N][K] bf16 per expert.
__global__ void transpose_cast_kernel(const float* __restrict__ routed,
                                      const float* __restrict__ shared_w,
                                      unsigned short* __restrict__ outb,
                                      int K, int N) {
  int e = blockIdx.z;
  const float* in = (e < NEXP) ? routed + (size_t)e * K * N : shared_w;
  unsigned short* out = outb + (size_t)e * K * N;
  __shared__ float tile[32][33];
  int n0 = blockIdx.x * 32, k0 = blockIdx.y * 32;
  int tid = threadIdx.x;
  int c = tid & 31, r0 = tid >> 5;
#pragma unroll
  for (int i = 0; i < 4; i++) {
    int r = r0 + i * 8;
    tile[r][c] = in[(size_t)(k0 + r) * N + n0 + c];
  }
  __syncthreads();
  int rr = tid >> 3;          // n-row within tile
  int c4 = (tid & 7) * 4;     // k group
  ushort4 o;
  o.x = f2b(tile[c4 + 0][rr]); o.y = f2b(tile[c4 + 1][rr]);
  o.z = f2b(tile[c4 + 2][rr]); o.w = f2b(tile[c4 + 3][rr]);
  *(ushort4*)(out + (size_t)(n0 + rr) * K + k0 + c4) = o;
}

// Router stage 1: fp32 logits, exact top-2 (lowest index on ties, like lax.top_k),
// softmax weight. No global atomics.
__global__ void router_topk_kernel(const float* __restrict__ x, const float* __restrict__ rw,
                                   int* __restrict__ top_idx, float* __restrict__ top_w) {
  int wv = threadIdx.x >> 6, lane = threadIdx.x & 63;
  int t = blockIdx.x * 4 + wv;
  const float* xr = x + (size_t)t * DIM;
  float a[8];
#pragma unroll
  for (int e = 0; e < 8; e++) a[e] = 0.f;
#pragma unroll
  for (int i = 0; i < 16; i++) {
    int d = i * 64 + lane;
    float xv = xr[d];
    float4 r0 = *(const float4*)(rw + d * 8);
    float4 r1 = *(const float4*)(rw + d * 8 + 4);
    a[0] += xv * r0.x; a[1] += xv * r0.y; a[2] += xv * r0.z; a[3] += xv * r0.w;
    a[4] += xv * r1.x; a[5] += xv * r1.y; a[6] += xv * r1.z; a[7] += xv * r1.w;
  }
#pragma unroll
  for (int s = 32; s; s >>= 1) {
#pragma unroll
    for (int e = 0; e < 8; e++) a[e] += __shfl_down(a[e], s);
  }
  if (lane == 0) {
    int be = 0; float bv = a[0];
#pragma unroll
    for (int e = 1; e < 8; e++) if (a[e] > bv) { bv = a[e]; be = e; }
    int be2 = -1; float bv2 = -3.4e38f;
#pragma unroll
    for (int e = 0; e < 8; e++) if (e != be && a[e] > bv2) { bv2 = a[e]; be2 = e; }
    float w0 = 1.f / (1.f + __expf(bv2 - bv));
    top_idx[t] = be | (be2 << 8);
    top_w[t] = w0;
  }
}

// Router stage 2: single-block bucket build (LDS atomics only) + prefix offsets.
__global__ void bucket_kernel(const int* __restrict__ top_idx, const float* __restrict__ top_w,
                              int* __restrict__ counts, int* __restrict__ offs,
                              int* __restrict__ tok_list, float* __restrict__ tok_w) {
  __shared__ int lcount[NEXP];
  int tid = threadIdx.x;
  if (tid < NEXP) lcount[tid] = 0;
  __syncthreads();
  for (int t = tid; t < T_TOKENS; t += 256) {
    int p = top_idx[t];
    float w0 = top_w[t];
    int e0 = p & 0xff, e1 = p >> 8;
    int s0 = atomicAdd(&lcount[e0], 1);
    tok_list[e0 * T_TOKENS + s0] = t; tok_w[e0 * T_TOKENS + s0] = w0;
    int s1 = atomicAdd(&lcount[e1], 1);
    tok_list[e1 * T_TOKENS + s1] = t; tok_w[e1 * T_TOKENS + s1] = 1.f - w0;
  }
  __syncthreads();
  if (tid == 0) {
    int run = 0;
    for (int e = 0; e < NEXP; e++) { counts[e] = lcount[e]; offs[e] = run; run += lcount[e]; }
    offs[NEXP] = run;  // == 2*T_TOKENS = 16384 always
  }
}

// PHASE 1: h[hbase+m] = relu(x_gathered[m] @ W1_e)      K=1024, nt=32
// PHASE 2: out[tok[m]] (+)= w[m] * (h[hbase+m] @ W2_e)  K=4096, batched: K-split 2, nt=64
// expert_arg >= 0: fixed expert, hbase=0, no K-split (serialized fallback).
// expert_arg <  0: batched; PHASE1 expert=z, PHASE2 expert=z%9, ksplit=z/9; accmode=1 -> atomicAdd.
//
// Tile 256x256, BK=32, 8 waves (2M x 4N), per-wave 128x64 = 8x4 16x16x32 MFMA frags.
// LDS: 4-deep ring of 16KB buffers for A and B (128 KB total). Within a buffer,
//   tile (256 rows x 32 K bf16) stored as 128 paired rows of 128 B:
//     LDS row r, chunk slot s holds global chunk g = s ^ (r&7);
//     tile row = 2r + (g>>2), k offset = (g&3)*8.  (R6: measured 0 bank conflicts.)
//   DMA dest linear (wave-uniform base + lane*16); SOURCE absorbs swizzle (rule #21).
// Pipeline: 3-tile lookahead, counted vmcnt (8 steady / 4 / 0 tail), raw s_barrier.
//   Tile t body = 2 phases (m201 template density):
//     A: ds_read af_lo[4]+bfr[4]; stage half(t+3); BAR; lgkm(0); schedbar;
//        prio1; 16 MFMA (mf0-3); prio0; BAR.
//     B: ds_read af_hi[4]; stage half(t+3); vmcnt(8); BAR; lgkm(0); schedbar;
//        prio1; 16 MFMA (mf4-7); prio0; BAR.
//   In-flight at steady vmcnt: tiles t+1(4), t+2(4), t+3(4) = 12 -> vmcnt(8)
//   retires tile t+1 before its phase-A reads. Tail: vmcnt(4), vmcnt(0), none.
//   WAR safety: each wave's lgkm(0) precedes its MFMA precedes the closing BAR,
//   so all reads of buf b complete before any wave can re-stage b (= (t-1)&3).
template <int PHASE>
__global__ __launch_bounds__(512, 2) void gemm_kernel(
    const unsigned short* __restrict__ A, const unsigned short* __restrict__ Wt,
    unsigned short* __restrict__ H, float* __restrict__ Out,
    const int* __restrict__ counts, const int* __restrict__ offs,
    const int* __restrict__ tok_list, const float* __restrict__ tok_w,
    int expert_arg, int accmode) {
  const int Kd = (PHASE == 1) ? DIM : INTER;
  int zz = (int)blockIdx.z;
  int expert, ksp;
  if (expert_arg >= 0) { expert = expert_arg; ksp = 0; }
  else if (PHASE == 2) { expert = zz % 9; ksp = zz / 9; }
  else { expert = zz; ksp = 0; }

  int count = (expert < NEXP) ? counts[expert] : T_TOKENS;
  int m0 = blockIdx.y * 256;
  if (m0 >= count) return;
  int n0 = blockIdx.x * 256;
  int hbase = (expert_arg >= 0) ? 0 : ((expert < NEXP) ? offs[expert] : 2 * T_TOKENS);
  const unsigned short* Bt = Wt + (size_t)expert * (4096 * 1024);

  int nt, k0base;
  if (PHASE == 1) { nt = 32; k0base = 0; }
  else if (expert_arg >= 0) { nt = 128; k0base = 0; }
  else { nt = 64; k0base = ksp * 2048; }

  // 4-deep ring: per buffer 256 rows x 32 K-elems bf16 = 16 KB. A: 64KB, B: 64KB.
  __shared__ __align__(16) unsigned short As[4][256 * 32];
  __shared__ __align__(16) unsigned short Bs[4][256 * 32];

  int tid = threadIdx.x;
  int wv = tid >> 6, lane = tid & 63;
  int wv_m = wv >> 2, wv_n = wv & 3;         // 2 x 4 wave grid
  int m_woff = wv_m * 128, n_woff = wv_n * 64;

  // ---- staging setup (identical to R6): 2 A-issues + 2 B-issues per tile ----
  int g = (lane & 7) ^ (lane >> 3);
  int kc = (g & 3) * 8;
  const unsigned short* aG[2];
  const unsigned short* bG[2];
  int ldsOff[2];
#pragma unroll
  for (int j = 0; j < 2; j++) {
    int tr = j * 128 + wv * 16 + 2 * (lane >> 3) + (g >> 2);   // tile row 0..255
    int srcA;
    if (PHASE == 1) {
      int m = m0 + tr;
      srcA = (expert < NEXP) ? ((m < count) ? tok_list[expert * T_TOKENS + m] : 0) : m;
    } else {
      srcA = hbase + m0 + tr;                // h rows bucket-ordered (garbage rows masked at store)
    }
    aG[j] = A + (size_t)srcA * Kd + k0base + kc;
    bG[j] = Bt + (size_t)(n0 + tr) * Kd + k0base + kc;
    ldsOff[j] = j * 4096 + wv * 512;         // elem offset of wave-uniform LDS base
  }

  f32x4 acc[8][4];
#pragma unroll
  for (int mf = 0; mf < 8; mf++)
#pragma unroll
    for (int nf = 0; nf < 4; nf++) acc[mf][nf] = (f32x4)0.f;

  // ---- frag-read addressing (identical to R6, measured 0 conflicts) ----
  int l15 = lane & 15, q = lane >> 4;
  int slot = (((l15 & 1) << 2) | q) ^ (l15 >> 1);
  int aBase = (wv_m * 64 + (l15 >> 1)) * 64 + slot * 8;   // elems; mf stride = 8 rows = 512
  int bBase = (wv_n * 32 + (l15 >> 1)) * 64 + slot * 8;   // elems; nf stride = 8 rows = 512

  bf16x8 af_lo[4], af_hi[4], bfr[4];

  auto stage = [&](int buf) {                // full 4-load stage (prologue only)
#pragma unroll
    for (int j = 0; j < 2; j++) {
      load_lds16(aG[j], &As[buf][ldsOff[j]]);
      load_lds16(bG[j], &Bs[buf][ldsOff[j]]);
      aG[j] += 32; bG[j] += 32;
    }
  };

  auto phaseA = [&](int buf, int sbuf, bool doStage) {
#pragma unroll
    for (int mf = 0; mf < 4; mf++) af_lo[mf] = *(const bf16x8*)&As[buf][aBase + mf * 512];
#pragma unroll
    for (int nf = 0; nf < 4; nf++) bfr[nf]  = *(const bf16x8*)&Bs[buf][bBase + nf * 512];
    if (doStage) {
      load_lds16(aG[0], &As[sbuf][ldsOff[0]]);
      load_lds16(bG[0], &Bs[sbuf][ldsOff[0]]);
      aG[0] += 32; bG[0] += 32;
    }
    ASM_BAR();
    ASM_LGKM0();
    __builtin_amdgcn_sched_barrier(0);
    __builtin_amdgcn_s_setprio(1);
#pragma unroll
    for (int mf = 0; mf < 4; mf++)
#pragma unroll
      for (int nf = 0; nf < 4; nf++)
        acc[mf][nf] = __builtin_amdgcn_mfma_f32_16x16x32_bf16(af_lo[mf], bfr[nf], acc[mf][nf], 0, 0, 0);
    __builtin_amdgcn_s_setprio(0);
    ASM_BAR();
  };

  auto phaseB_pre = [&](int buf, int sbuf, bool doStage) {
#pragma unroll
    for (int mf = 0; mf < 4; mf++) af_hi[mf] = *(const bf16x8*)&As[buf][aBase + 2048 + mf * 512];
    if (doStage) {
      load_lds16(aG[1], &As[sbuf][ldsOff[1]]);
      load_lds16(bG[1], &Bs[sbuf][ldsOff[1]]);
      aG[1] += 32; bG[1] += 32;
    }
  };

  auto phaseB_post = [&]() {
    ASM_BAR();
    ASM_LGKM0();
    __builtin_amdgcn_sched_barrier(0);
    __builtin_amdgcn_s_setprio(1);
#pragma unroll
    for (int mf = 0; mf < 4; mf++)
#pragma unroll
      for (int nf = 0; nf < 4; nf++)
        acc[4 + mf][nf] = __builtin_amdgcn_mfma_f32_16x16x32_bf16(af_hi[mf], bfr[nf], acc[4 + mf][nf], 0, 0, 0);
    __builtin_amdgcn_s_setprio(0);
    ASM_BAR();
  };

  // ---- pipelined K loop (nt >= 4 always: 32/64/128) ----
  stage(0); stage(1); stage(2);
  ASM_VMCNT(8); ASM_BAR();                   // 12 in flight -> tile 0 landed, published
  int t = 0;
  for (; t + 3 < nt; ++t) {
    int buf = t & 3, sbuf = (t + 3) & 3;     // sbuf == (t-1)&3: freed by tile t-1's last BAR
    phaseA(buf, sbuf, true);
    phaseB_pre(buf, sbuf, true);
    ASM_VMCNT(8);                            // 12 in flight -> retires tile t+1's 4 loads
    phaseB_post();
  }
  phaseA(t & 3, 0, false); phaseB_pre(t & 3, 0, false); ASM_VMCNT(4); phaseB_post(); ++t;
  phaseA(t & 3, 0, false); phaseB_pre(t & 3, 0, false); ASM_VMCNT(0); phaseB_post(); ++t;
  phaseA(t & 3, 0, false); phaseB_pre(t & 3, 0, false); phaseB_post();

  // C/D layout (m89-verified): col = lane&15, row = (lane>>4)*4 + i
  if (PHASE == 1) {
#pragma unroll
    for (int mf = 0; mf < 8; mf++)
#pragma unroll
      for (int i = 0; i < 4; i++) {
        int m = m0 + m_woff + mf * 16 + q * 4 + i;
        if (m < count) {
#pragma unroll
          for (int nf = 0; nf < 4; nf++) {
            int f = n0 + n_woff + nf * 16 + l15;
            float v = acc[mf][nf][i];
            H[(size_t)(hbase + m) * INTER + f] = f2b(v > 0.f ? v : 0.f);
          }
        }
      }
  } else {
#pragma unroll
    for (int mf = 0; mf < 8; mf++)
#pragma unroll
      for (int i = 0; i < 4; i++) {
        int m = m0 + m_woff + mf * 16 + q * 4 + i;
        if (m < count) {
          int tokn; float swt;
          if (expert < NEXP) { tokn = tok_list[expert * T_TOKENS + m]; swt = tok_w[expert * T_TOKENS + m]; }
          else { tokn = m; swt = 1.f; }
          float* orow = Out + (size_t)tokn * DIM;
#pragma unroll
          for (int nf = 0; nf < 4; nf++) {
            int d = n0 + n_woff + nf * 16 + l15;
            float v = swt * acc[mf][nf][i];
            if (accmode) atomicAdd(orow + d, v);          // batched: out pre-zeroed, K-split safe
            else if (expert < NEXP) orow[d] += v;          // serialized routed
            else orow[d] = v;                              // serialized shared (init)
          }
        }
      }
  }
}

extern "C" void kernel_launch(void* const* d_in, const int* in_sizes, int n_in,
                              void* d_out, int out_size, void* d_ws, size_t ws_size,
                              hipStream_t stream) {
  const float* x   = (const float*)d_in[0];
  const float* sw1 = (const float*)d_in[1];
  const float* sw2 = (const float*)d_in[2];
  const float* rw1 = (const float*)d_in[3];
  const float* rw2 = (const float*)d_in[4];
  const float* rtw = (const float*)d_in[5];
  float* out = (float*)d_out;

  char* ws = (char*)d_ws;
  unsigned short* xb  = (unsigned short*)(ws);
  unsigned short* w1t = (unsigned short*)(ws + 16777216);
  unsigned short* w2t = (unsigned short*)(ws + 92274688);
  unsigned short* h   = (unsigned short*)(ws + 167772160);
  // router scratch overlaid on head of h (consumed by bucket_kernel before h is written)
  int*   top_idx      = (int*)(ws + 167772160);
  float* top_w        = (float*)(ws + 167772160 + 32768);

  const size_t H_BIG  = (size_t)24576 * 4096 * 2;        // 201,326,592
  const size_t H_SMALL= (size_t)8192  * 4096 * 2;        //  67,108,864
  const size_t NEED_BIG = 167772160 + H_BIG + 262144 * 2 + 256;
  bool big = ws_size >= NEED_BIG;
  size_t tail = 167772160 + (big ? H_BIG : H_SMALL);
  int*   tok_list = (int*)(ws + tail);
  float* tok_w    = (float*)(ws + tail + 262144);
  int*   counts   = (int*)(ws + tail + 524288);
  int*   offs     = (int*)(ws + tail + 524288 + 64);

  cast_x_kernel<<<(T_TOKENS * DIM) / (256 * 4), 256, 0, stream>>>(x, xb);
  transpose_cast_kernel<<<dim3(128, 32, 9), 256, 0, stream>>>(rw1, sw1, w1t, 1024, 4096);
  transpose_cast_kernel<<<dim3(32, 128, 9), 256, 0, stream>>>(rw2, sw2, w2t, 4096, 1024);
  router_topk_kernel<<<T_TOKENS / 4, 256, 0, stream>>>(x, rtw, top_idx, top_w);
  bucket_kernel<<<1, 256, 0, stream>>>(top_idx, top_w, counts, offs, tok_list, tok_w);

  if (big) {
    hipMemsetAsync(out, 0, (size_t)T_TOKENS * DIM * sizeof(float), stream);
    // all 9 experts (z=8 is shared), one launch per phase; p2 K-split=2 (z=18), atomic acc.
    gemm_kernel<1><<<dim3(16, 32, 9), 512, 0, stream>>>(xb, w1t, h, nullptr,
                                                        counts, offs, tok_list, tok_w, -1, 1);
    gemm_kernel<2><<<dim3(4, 32, 18), 512, 0, stream>>>(h, w2t, nullptr, out,
                                                        counts, offs, tok_list, tok_w, -1, 1);
  } else {
    // serialized fallback: shared first (plain-store init), routed accumulate
    gemm_kernel<1><<<dim3(16, 32), 512, 0, stream>>>(xb, w1t, h, nullptr,
                                                     counts, offs, tok_list, tok_w, 8, 0);
    gemm_kernel<2><<<dim3(4, 32), 512, 0, stream>>>(h, w2t, nullptr, out,
                                                    counts, offs, tok_list, tok_w, 8, 0);
    for (int e = 0; e < 8; e++) {
      gemm_kernel<1><<<dim3(16, 32), 512, 0, stream>>>(xb, w1t, h, nullptr,
                                                       counts, offs, tok_list, tok_w, e, 0);
      gemm_kernel<2><<<dim3(4, 32), 512, 0, stream>>>(h, w2t, nullptr, out,
                                                      counts, offs, tok_list, tok_w, e, 0);
    }
  }
}